// Round 7
// baseline (1438.395 us; speedup 1.0000x reference)
//
#include <hip/hip_runtime.h>

// HyperMixer fused kernel, MI355X (gfx950).
// x[B=2,S=4096,K=4,D=2048] f32, out[B,S,D] f32, W[24][8192] f32,
// scale[3], base[24]. Output = concat(y[B,S,K,D], collapsed[B,S,D]) f32.
//
// Round-7: 2 tokens per 512-thread block. x staged in LDS as packed f16
// (16 KB/token); W pre-converted to f16 (384 KB, L2-resident). Phase A:
// wave w computes rows 3w..3w+2 for BOTH tokens against one W load
// (halves W L2 traffic vs r6) using v_dot2_f32_f16 (no unpack VALU).
// Phase B reads f16 x back (rel err 2^-11 < bf16's 2^-9 -> absmax should
// DROP vs r6's 0.0625). Sumsq for RMS uses the exact f32 loads.
// r6 evidence: VALUBusy 46% (bf16 unpack+fma ~1550 ops/thr), W L2 3.1 GB,
// HBM only 25% -> cut VALU 3x and W traffic 2x, raise occupancy to 8 w/SIMD.

#define EPS 1e-6f
constexpr int K_ = 4, D_ = 2048, KD = 8192, NOUT = 24;
constexpr int NTOK = 2 * 4096;          // 8192 tokens
constexpr int TPB = 512;

typedef _Float16 h2 __attribute__((ext_vector_type(2)));

static __device__ __forceinline__ unsigned int pk2(float a, float b) {
    h2 h; h.x = (_Float16)a; h.y = (_Float16)b;
    return __builtin_bit_cast(unsigned int, h);
}

static __device__ __forceinline__ float dot2(unsigned int w, unsigned int x, float c) {
#if __has_builtin(__builtin_amdgcn_fdot2)
    return __builtin_amdgcn_fdot2(__builtin_bit_cast(h2, w),
                                  __builtin_bit_cast(h2, x), c, false);
#else
    h2 hw = __builtin_bit_cast(h2, w), hx = __builtin_bit_cast(h2, x);
    return c + (float)hw.x * (float)hx.x + (float)hw.y * (float)hx.y;
#endif
}

// Wh: linear f16 of W. Thread g converts 8 consecutive floats.
__global__ void conv_w_kernel(const float* __restrict__ W, unsigned int* __restrict__ Wh) {
    int g = blockIdx.x * blockDim.x + threadIdx.x;   // 24576 threads
    const float* src = W + (size_t)g * 8;
    float4 a = *reinterpret_cast<const float4*>(src);
    float4 b = *reinterpret_cast<const float4*>(src + 4);
    uint4 u;
    u.x = pk2(a.x, a.y); u.y = pk2(a.z, a.w);
    u.z = pk2(b.x, b.y); u.w = pk2(b.z, b.w);
    *reinterpret_cast<uint4*>(Wh + (size_t)g * 4) = u;
}

template <bool FH>
__global__ __launch_bounds__(TPB, 8) void hypermix_kernel(
    const float* __restrict__ x, const float* __restrict__ outp,
    const unsigned int* __restrict__ Wh, const float* __restrict__ Wf,
    const float* __restrict__ scale, const float* __restrict__ base,
    float* __restrict__ y, float* __restrict__ coll)
{
    const int t = threadIdx.x;
    const int w = t >> 6, lane = t & 63;
    const int tk = t >> 8;          // token this thread stages / combines
    const int t8 = t & 255;
    const size_t gt0 = (size_t)blockIdx.x * 2;

    __shared__ unsigned int xh[2][KD / 2];  // packed f16 x, 16 KB per token
    __shared__ float ssred[8];              // per-wave sumsq partials
    __shared__ float lg[2][24];             // raw dot products
    __shared__ float wts[2][24];            // 0..3 pre, 4..7 post, 8..23 comb

    // ---- phase 0: stage x into LDS as f16, sumsq from exact f32 ----
    {
        const float* xb = x + (gt0 + tk) * KD + t8 * 4;
        float ss = 0.f;
#pragma unroll
        for (int i = 0; i < 8; ++i) {
            float4 v = *reinterpret_cast<const float4*>(xb + i * 1024);
            ss += v.x * v.x + v.y * v.y + v.z * v.z + v.w * v.w;
            uint2 p; p.x = pk2(v.x, v.y); p.y = pk2(v.z, v.w);
            *reinterpret_cast<uint2*>(&xh[tk][i * 512 + t8 * 2]) = p;
        }
#pragma unroll
        for (int m = 1; m < 64; m <<= 1) ss += __shfl_xor(ss, m, 64);
        if (lane == 0) ssred[w] = ss;
    }
    __syncthreads();

    // ---- phase A: wave w -> rows 3w..3w+2, BOTH tokens (shared W load) ----
    {
        const int r0 = w * 3;
        float acc[3][2];
#pragma unroll
        for (int j = 0; j < 3; ++j) { acc[j][0] = 0.f; acc[j][1] = 0.f; }

        for (int it = 0; it < 16; ++it) {
            const int gi = it * 64 + lane;          // uint4 group = 8 f16
            uint4 xa = *reinterpret_cast<const uint4*>(&xh[0][gi * 4]);
            uint4 xb = *reinterpret_cast<const uint4*>(&xh[1][gi * 4]);
#pragma unroll
            for (int j = 0; j < 3; ++j) {
                if (FH) {
                    uint4 wv = *reinterpret_cast<const uint4*>(
                        Wh + ((size_t)(r0 + j) * 4096 + gi * 4));
                    acc[j][0] = dot2(wv.x, xa.x, acc[j][0]);
                    acc[j][0] = dot2(wv.y, xa.y, acc[j][0]);
                    acc[j][0] = dot2(wv.z, xa.z, acc[j][0]);
                    acc[j][0] = dot2(wv.w, xa.w, acc[j][0]);
                    acc[j][1] = dot2(wv.x, xb.x, acc[j][1]);
                    acc[j][1] = dot2(wv.y, xb.y, acc[j][1]);
                    acc[j][1] = dot2(wv.z, xb.z, acc[j][1]);
                    acc[j][1] = dot2(wv.w, xb.w, acc[j][1]);
                } else {
                    const float* wr = Wf + (size_t)(r0 + j) * KD + gi * 8;
                    float4 w0 = *reinterpret_cast<const float4*>(wr);
                    float4 w1 = *reinterpret_cast<const float4*>(wr + 4);
                    h2 a0 = __builtin_bit_cast(h2, xa.x), a1 = __builtin_bit_cast(h2, xa.y);
                    h2 a2 = __builtin_bit_cast(h2, xa.z), a3 = __builtin_bit_cast(h2, xa.w);
                    h2 b0 = __builtin_bit_cast(h2, xb.x), b1 = __builtin_bit_cast(h2, xb.y);
                    h2 b2 = __builtin_bit_cast(h2, xb.z), b3 = __builtin_bit_cast(h2, xb.w);
                    acc[j][0] += w0.x * (float)a0.x + w0.y * (float)a0.y
                               + w0.z * (float)a1.x + w0.w * (float)a1.y
                               + w1.x * (float)a2.x + w1.y * (float)a2.y
                               + w1.z * (float)a3.x + w1.w * (float)a3.y;
                    acc[j][1] += w0.x * (float)b0.x + w0.y * (float)b0.y
                               + w0.z * (float)b1.x + w0.w * (float)b1.y
                               + w1.x * (float)b2.x + w1.y * (float)b2.y
                               + w1.z * (float)b3.x + w1.w * (float)b3.y;
                }
            }
        }
#pragma unroll
        for (int j = 0; j < 3; ++j)
#pragma unroll
            for (int tt = 0; tt < 2; ++tt) {
                float v = acc[j][tt];
#pragma unroll
                for (int m = 1; m < 64; m <<= 1) v += __shfl_xor(v, m, 64);
                if (lane == 0) lg[tt][r0 + j] = v;
            }
    }
    __syncthreads();

    // ---- weights: 32 lanes (16 per token), sigmoid/softmax/sinkhorn ----
    if (t < 32) {
        const int wtk = t >> 4, idx = t & 15;     // idx = h*4 + k
        float ss = ssred[wtk * 4] + ssred[wtk * 4 + 1]
                 + ssred[wtk * 4 + 2] + ssred[wtk * 4 + 3];
        float rms = rsqrtf(ss * (1.f / 8192.f) + EPS);
        float s0 = scale[0], s1 = scale[1], s2 = scale[2];
        float cl = lg[wtk][8 + idx] * rms * s2 + base[8 + idx];
        float mx = fmaxf(cl, __shfl_xor(cl, 1, 64));
        mx = fmaxf(mx, __shfl_xor(mx, 2, 64));
        float e = expf(cl - mx);
        float se = e + __shfl_xor(e, 1, 64); se += __shfl_xor(se, 2, 64);
        float m = e / se + EPS;
        float cs = m + __shfl_xor(m, 4, 64); cs += __shfl_xor(cs, 8, 64);
        m = m / (cs + EPS);
#pragma unroll
        for (int it = 0; it < 19; ++it) {
            float rs = m + __shfl_xor(m, 1, 64); rs += __shfl_xor(rs, 2, 64);
            m = m / (rs + EPS);
            cs = m + __shfl_xor(m, 4, 64); cs += __shfl_xor(cs, 8, 64);
            m = m / (cs + EPS);
        }
        wts[wtk][8 + idx] = m;
        if (idx < 4) {
            float z = lg[wtk][idx] * rms * s0 + base[idx];
            wts[wtk][idx] = 1.f / (1.f + expf(-z)) + EPS;
        } else if (idx < 8) {
            float z = lg[wtk][idx] * rms * s1 + base[idx];
            wts[wtk][idx] = 2.f / (1.f + expf(-z));
        }
    }
    __syncthreads();

    // ---- phase B: outputs from f16 x in LDS ----
    float pre[4], post[4], cmb[4][4];
#pragma unroll
    for (int k = 0; k < 4; ++k) { pre[k] = wts[tk][k]; post[k] = wts[tk][4 + k]; }
#pragma unroll
    for (int h = 0; h < 4; ++h)
#pragma unroll
        for (int k = 0; k < 4; ++k) cmb[h][k] = wts[tk][8 + h * 4 + k];

    const float* ob = outp + (gt0 + tk) * D_;
    float* yb = y + (gt0 + tk) * KD;
    float* cb = coll + (gt0 + tk) * D_;

#pragma unroll
    for (int dh = 0; dh < 2; ++dh) {
        const int d = dh * 1024 + t8 * 4;
        float xk[4][4];
#pragma unroll
        for (int k = 0; k < 4; ++k) {
            uint2 p = *reinterpret_cast<const uint2*>(&xh[tk][k * 1024 + (d >> 1)]);
            h2 h0 = __builtin_bit_cast(h2, p.x), h1 = __builtin_bit_cast(h2, p.y);
            xk[k][0] = (float)h0.x; xk[k][1] = (float)h0.y;
            xk[k][2] = (float)h1.x; xk[k][3] = (float)h1.y;
        }
        float4 ov = *reinterpret_cast<const float4*>(ob + d);
        float cv[4], yv[4];
#pragma unroll
        for (int e = 0; e < 4; ++e)
            cv[e] = pre[0] * xk[0][e] + pre[1] * xk[1][e]
                  + pre[2] * xk[2][e] + pre[3] * xk[3][e];
        *reinterpret_cast<float4*>(cb + d) = make_float4(cv[0], cv[1], cv[2], cv[3]);
        const float oe[4] = {ov.x, ov.y, ov.z, ov.w};
#pragma unroll
        for (int h = 0; h < 4; ++h) {
#pragma unroll
            for (int e = 0; e < 4; ++e)
                yv[e] = post[h] * oe[e] + cmb[h][0] * xk[0][e] + cmb[h][1] * xk[1][e]
                      + cmb[h][2] * xk[2][e] + cmb[h][3] * xk[3][e];
            *reinterpret_cast<float4*>(yb + h * D_ + d) =
                make_float4(yv[0], yv[1], yv[2], yv[3]);
        }
    }
}

extern "C" void kernel_launch(void* const* d_in, const int* in_sizes, int n_in,
                              void* d_out, int out_size, void* d_ws, size_t ws_size,
                              hipStream_t stream) {
    const float* x     = (const float*)d_in[0];
    const float* outp  = (const float*)d_in[1];
    const float* W     = (const float*)d_in[2];
    const float* scale = (const float*)d_in[3];
    const float* base  = (const float*)d_in[4];
    float* y    = (float*)d_out;
    float* coll = y + (size_t)NTOK * KD;   // 67108864

    const size_t wh_bytes = (size_t)NOUT * KD * 2; // 384 KB f16
    if (ws_size >= wh_bytes) {
        unsigned int* Wh = (unsigned int*)d_ws;
        conv_w_kernel<<<NOUT * KD / 8 / 256, 256, 0, stream>>>(W, Wh);
        hypermix_kernel<true><<<NTOK / 2, TPB, 0, stream>>>(x, outp, Wh, W, scale, base, y, coll);
    } else {
        hypermix_kernel<false><<<NTOK / 2, TPB, 0, stream>>>(x, outp, nullptr, W, scale, base, y, coll);
    }
}

// Round 8
// 1006.521 us; speedup vs baseline: 1.4291x; 1.4291x over previous
//
#include <hip/hip_runtime.h>

// HyperMixer fused kernel, MI355X (gfx950).
// x[B=2,S=4096,K=4,D=2048] f32, out[B,S,D] f32, W[24][8192] f32,
// scale[3], base[24]. Output = concat(y[B,S,K,D], collapsed[B,S,D]) f32.
//
// Round-8 = round-7 with the launch-bounds bug fixed. r7's
// __launch_bounds__(512,8) forced a 32-VGPR cap -> full spill (FETCH 2.5GB,
// WRITE 2.7GB scratch, 1438us). Body needs ~60 VGPR; (512,4) gives a
// 128-VGPR budget (2 blocks/CU, 16 waves/CU) with LDS 33KB not limiting.
// Structure (validated r7: absmax 0.03125): 2 tokens/512-thread block,
// x as packed f16 in LDS, W pre-converted f16 (L2-resident), wave w does
// rows 3w..3w+2 for BOTH tokens (one W load serves 2 tokens), v_dot2_f32_f16.

#define EPS 1e-6f
constexpr int K_ = 4, D_ = 2048, KD = 8192, NOUT = 24;
constexpr int NTOK = 2 * 4096;          // 8192 tokens
constexpr int TPB = 512;

typedef _Float16 h2 __attribute__((ext_vector_type(2)));

static __device__ __forceinline__ unsigned int pk2(float a, float b) {
    h2 h; h.x = (_Float16)a; h.y = (_Float16)b;
    return __builtin_bit_cast(unsigned int, h);
}

static __device__ __forceinline__ float dot2(unsigned int w, unsigned int x, float c) {
#if __has_builtin(__builtin_amdgcn_fdot2)
    return __builtin_amdgcn_fdot2(__builtin_bit_cast(h2, w),
                                  __builtin_bit_cast(h2, x), c, false);
#else
    h2 hw = __builtin_bit_cast(h2, w), hx = __builtin_bit_cast(h2, x);
    return c + (float)hw.x * (float)hx.x + (float)hw.y * (float)hx.y;
#endif
}

// Wh: linear f16 of W. Thread g converts 8 consecutive floats.
__global__ void conv_w_kernel(const float* __restrict__ W, unsigned int* __restrict__ Wh) {
    int g = blockIdx.x * blockDim.x + threadIdx.x;   // 24576 threads
    const float* src = W + (size_t)g * 8;
    float4 a = *reinterpret_cast<const float4*>(src);
    float4 b = *reinterpret_cast<const float4*>(src + 4);
    uint4 u;
    u.x = pk2(a.x, a.y); u.y = pk2(a.z, a.w);
    u.z = pk2(b.x, b.y); u.w = pk2(b.z, b.w);
    *reinterpret_cast<uint4*>(Wh + (size_t)g * 4) = u;
}

template <bool FH>
__global__ __launch_bounds__(TPB, 4) void hypermix_kernel(
    const float* __restrict__ x, const float* __restrict__ outp,
    const unsigned int* __restrict__ Wh, const float* __restrict__ Wf,
    const float* __restrict__ scale, const float* __restrict__ base,
    float* __restrict__ y, float* __restrict__ coll)
{
    const int t = threadIdx.x;
    const int w = t >> 6, lane = t & 63;
    const int tk = t >> 8;          // token this thread stages / combines
    const int t8 = t & 255;
    const size_t gt0 = (size_t)blockIdx.x * 2;

    __shared__ unsigned int xh[2][KD / 2];  // packed f16 x, 16 KB per token
    __shared__ float ssred[8];              // per-wave sumsq partials
    __shared__ float lg[2][24];             // raw dot products
    __shared__ float wts[2][24];            // 0..3 pre, 4..7 post, 8..23 comb

    // ---- phase 0: stage x into LDS as f16, sumsq from exact f32 ----
    {
        const float* xb = x + (gt0 + tk) * KD + t8 * 4;
        float ss = 0.f;
#pragma unroll
        for (int i = 0; i < 8; ++i) {
            float4 v = *reinterpret_cast<const float4*>(xb + i * 1024);
            ss += v.x * v.x + v.y * v.y + v.z * v.z + v.w * v.w;
            uint2 p; p.x = pk2(v.x, v.y); p.y = pk2(v.z, v.w);
            *reinterpret_cast<uint2*>(&xh[tk][i * 512 + t8 * 2]) = p;
        }
#pragma unroll
        for (int m = 1; m < 64; m <<= 1) ss += __shfl_xor(ss, m, 64);
        if (lane == 0) ssred[w] = ss;
    }
    __syncthreads();

    // ---- phase A: wave w -> rows 3w..3w+2, BOTH tokens (shared W load) ----
    {
        const int r0 = w * 3;
        float acc[3][2];
#pragma unroll
        for (int j = 0; j < 3; ++j) { acc[j][0] = 0.f; acc[j][1] = 0.f; }

        for (int it = 0; it < 16; ++it) {
            const int gi = it * 64 + lane;          // uint4 group = 8 f16
            uint4 xa = *reinterpret_cast<const uint4*>(&xh[0][gi * 4]);
            uint4 xb = *reinterpret_cast<const uint4*>(&xh[1][gi * 4]);
#pragma unroll
            for (int j = 0; j < 3; ++j) {
                if (FH) {
                    uint4 wv = *reinterpret_cast<const uint4*>(
                        Wh + ((size_t)(r0 + j) * 4096 + gi * 4));
                    acc[j][0] = dot2(wv.x, xa.x, acc[j][0]);
                    acc[j][0] = dot2(wv.y, xa.y, acc[j][0]);
                    acc[j][0] = dot2(wv.z, xa.z, acc[j][0]);
                    acc[j][0] = dot2(wv.w, xa.w, acc[j][0]);
                    acc[j][1] = dot2(wv.x, xb.x, acc[j][1]);
                    acc[j][1] = dot2(wv.y, xb.y, acc[j][1]);
                    acc[j][1] = dot2(wv.z, xb.z, acc[j][1]);
                    acc[j][1] = dot2(wv.w, xb.w, acc[j][1]);
                } else {
                    const float* wr = Wf + (size_t)(r0 + j) * KD + gi * 8;
                    float4 w0 = *reinterpret_cast<const float4*>(wr);
                    float4 w1 = *reinterpret_cast<const float4*>(wr + 4);
                    h2 a0 = __builtin_bit_cast(h2, xa.x), a1 = __builtin_bit_cast(h2, xa.y);
                    h2 a2 = __builtin_bit_cast(h2, xa.z), a3 = __builtin_bit_cast(h2, xa.w);
                    h2 b0 = __builtin_bit_cast(h2, xb.x), b1 = __builtin_bit_cast(h2, xb.y);
                    h2 b2 = __builtin_bit_cast(h2, xb.z), b3 = __builtin_bit_cast(h2, xb.w);
                    acc[j][0] += w0.x * (float)a0.x + w0.y * (float)a0.y
                               + w0.z * (float)a1.x + w0.w * (float)a1.y
                               + w1.x * (float)a2.x + w1.y * (float)a2.y
                               + w1.z * (float)a3.x + w1.w * (float)a3.y;
                    acc[j][1] += w0.x * (float)b0.x + w0.y * (float)b0.y
                               + w0.z * (float)b1.x + w0.w * (float)b1.y
                               + w1.x * (float)b2.x + w1.y * (float)b2.y
                               + w1.z * (float)b3.x + w1.w * (float)b3.y;
                }
            }
        }
#pragma unroll
        for (int j = 0; j < 3; ++j)
#pragma unroll
            for (int tt = 0; tt < 2; ++tt) {
                float v = acc[j][tt];
#pragma unroll
                for (int m = 1; m < 64; m <<= 1) v += __shfl_xor(v, m, 64);
                if (lane == 0) lg[tt][r0 + j] = v;
            }
    }
    __syncthreads();

    // ---- weights: 32 lanes (16 per token), sigmoid/softmax/sinkhorn ----
    if (t < 32) {
        const int wtk = t >> 4, idx = t & 15;     // idx = h*4 + k
        float ss = ssred[wtk * 4] + ssred[wtk * 4 + 1]
                 + ssred[wtk * 4 + 2] + ssred[wtk * 4 + 3];
        float rms = rsqrtf(ss * (1.f / 8192.f) + EPS);
        float s0 = scale[0], s1 = scale[1], s2 = scale[2];
        float cl = lg[wtk][8 + idx] * rms * s2 + base[8 + idx];
        float mx = fmaxf(cl, __shfl_xor(cl, 1, 64));
        mx = fmaxf(mx, __shfl_xor(mx, 2, 64));
        float e = expf(cl - mx);
        float se = e + __shfl_xor(e, 1, 64); se += __shfl_xor(se, 2, 64);
        float m = e / se + EPS;
        float cs = m + __shfl_xor(m, 4, 64); cs += __shfl_xor(cs, 8, 64);
        m = m / (cs + EPS);
#pragma unroll
        for (int it = 0; it < 19; ++it) {
            float rs = m + __shfl_xor(m, 1, 64); rs += __shfl_xor(rs, 2, 64);
            m = m / (rs + EPS);
            cs = m + __shfl_xor(m, 4, 64); cs += __shfl_xor(cs, 8, 64);
            m = m / (cs + EPS);
        }
        wts[wtk][8 + idx] = m;
        if (idx < 4) {
            float z = lg[wtk][idx] * rms * s0 + base[idx];
            wts[wtk][idx] = 1.f / (1.f + expf(-z)) + EPS;
        } else if (idx < 8) {
            float z = lg[wtk][idx] * rms * s1 + base[idx];
            wts[wtk][idx] = 2.f / (1.f + expf(-z));
        }
    }
    __syncthreads();

    // ---- phase B: outputs from f16 x in LDS ----
    float pre[4], post[4], cmb[4][4];
#pragma unroll
    for (int k = 0; k < 4; ++k) { pre[k] = wts[tk][k]; post[k] = wts[tk][4 + k]; }
#pragma unroll
    for (int h = 0; h < 4; ++h)
#pragma unroll
        for (int k = 0; k < 4; ++k) cmb[h][k] = wts[tk][8 + h * 4 + k];

    const float* ob = outp + (gt0 + tk) * D_;
    float* yb = y + (gt0 + tk) * KD;
    float* cb = coll + (gt0 + tk) * D_;

#pragma unroll
    for (int dh = 0; dh < 2; ++dh) {
        const int d = dh * 1024 + t8 * 4;
        float xk[4][4];
#pragma unroll
        for (int k = 0; k < 4; ++k) {
            uint2 p = *reinterpret_cast<const uint2*>(&xh[tk][k * 1024 + (d >> 1)]);
            h2 h0 = __builtin_bit_cast(h2, p.x), h1 = __builtin_bit_cast(h2, p.y);
            xk[k][0] = (float)h0.x; xk[k][1] = (float)h0.y;
            xk[k][2] = (float)h1.x; xk[k][3] = (float)h1.y;
        }
        float4 ov = *reinterpret_cast<const float4*>(ob + d);
        float cv[4], yv[4];
#pragma unroll
        for (int e = 0; e < 4; ++e)
            cv[e] = pre[0] * xk[0][e] + pre[1] * xk[1][e]
                  + pre[2] * xk[2][e] + pre[3] * xk[3][e];
        *reinterpret_cast<float4*>(cb + d) = make_float4(cv[0], cv[1], cv[2], cv[3]);
        const float oe[4] = {ov.x, ov.y, ov.z, ov.w};
#pragma unroll
        for (int h = 0; h < 4; ++h) {
#pragma unroll
            for (int e = 0; e < 4; ++e)
                yv[e] = post[h] * oe[e] + cmb[h][0] * xk[0][e] + cmb[h][1] * xk[1][e]
                      + cmb[h][2] * xk[2][e] + cmb[h][3] * xk[3][e];
            *reinterpret_cast<float4*>(yb + h * D_ + d) =
                make_float4(yv[0], yv[1], yv[2], yv[3]);
        }
    }
}

extern "C" void kernel_launch(void* const* d_in, const int* in_sizes, int n_in,
                              void* d_out, int out_size, void* d_ws, size_t ws_size,
                              hipStream_t stream) {
    const float* x     = (const float*)d_in[0];
    const float* outp  = (const float*)d_in[1];
    const float* W     = (const float*)d_in[2];
    const float* scale = (const float*)d_in[3];
    const float* base  = (const float*)d_in[4];
    float* y    = (float*)d_out;
    float* coll = y + (size_t)NTOK * KD;   // 67108864

    const size_t wh_bytes = (size_t)NOUT * KD * 2; // 384 KB f16
    if (ws_size >= wh_bytes) {
        unsigned int* Wh = (unsigned int*)d_ws;
        conv_w_kernel<<<NOUT * KD / 8 / 256, 256, 0, stream>>>(W, Wh);
        hypermix_kernel<true><<<NTOK / 2, TPB, 0, stream>>>(x, outp, Wh, W, scale, base, y, coll);
    } else {
        hypermix_kernel<false><<<NTOK / 2, TPB, 0, stream>>>(x, outp, nullptr, W, scale, base, y, coll);
    }
}

// Round 9
// 469.226 us; speedup vs baseline: 3.0655x; 2.1451x over previous
//
#include <hip/hip_runtime.h>

// HyperMixer fused kernel, MI355X (gfx950).
// x[B=2,S=4096,K=4,D=2048] f32, out[B,S,D] f32, W[24][8192] f32,
// scale[3], base[24]. Output = concat(y[B,S,K,D], collapsed[B,S,D]) f32.
//
// Round-9 = round-8 algorithm with NO __launch_bounds__ occupancy arg.
// Empirical (r7/r8): arg2 acts as min BLOCKS/CU on this toolchain:
//   r7 (512,8): cap 32 VGPR (64 waves/CU), r8 (512,4): cap 64 VGPR —
// both forced multi-GB scratch spill. r6 with bare __launch_bounds__(512)
// allocated 56 VGPR, zero spill. So: let the allocator pick.
// Algorithm (validated r7/r8, absmax 0.03125): 2 tokens per 512-thread
// block; x staged in LDS as packed f16 (16 KB/token); W pre-converted f16
// (384 KB, L2-resident); wave w computes rows 3w..3w+2 for BOTH tokens
// (one W load serves 2 tokens -> 1.6 GB L2 W traffic); v_dot2_f32_f16
// does 2 MACs/inst with no unpack VALU.

#define EPS 1e-6f
constexpr int K_ = 4, D_ = 2048, KD = 8192, NOUT = 24;
constexpr int NTOK = 2 * 4096;          // 8192 tokens
constexpr int TPB = 512;

typedef _Float16 h2 __attribute__((ext_vector_type(2)));

static __device__ __forceinline__ unsigned int pk2(float a, float b) {
    h2 h; h.x = (_Float16)a; h.y = (_Float16)b;
    return __builtin_bit_cast(unsigned int, h);
}

static __device__ __forceinline__ float dot2(unsigned int w, unsigned int x, float c) {
#if __has_builtin(__builtin_amdgcn_fdot2)
    return __builtin_amdgcn_fdot2(__builtin_bit_cast(h2, w),
                                  __builtin_bit_cast(h2, x), c, false);
#else
    h2 hw = __builtin_bit_cast(h2, w), hx = __builtin_bit_cast(h2, x);
    return c + (float)hw.x * (float)hx.x + (float)hw.y * (float)hx.y;
#endif
}

// Wh: linear f16 of W. Thread g converts 8 consecutive floats.
__global__ void conv_w_kernel(const float* __restrict__ W, unsigned int* __restrict__ Wh) {
    int g = blockIdx.x * blockDim.x + threadIdx.x;   // 24576 threads
    const float* src = W + (size_t)g * 8;
    float4 a = *reinterpret_cast<const float4*>(src);
    float4 b = *reinterpret_cast<const float4*>(src + 4);
    uint4 u;
    u.x = pk2(a.x, a.y); u.y = pk2(a.z, a.w);
    u.z = pk2(b.x, b.y); u.w = pk2(b.z, b.w);
    *reinterpret_cast<uint4*>(Wh + (size_t)g * 4) = u;
}

template <bool FH>
__global__ __launch_bounds__(TPB) void hypermix_kernel(
    const float* __restrict__ x, const float* __restrict__ outp,
    const unsigned int* __restrict__ Wh, const float* __restrict__ Wf,
    const float* __restrict__ scale, const float* __restrict__ base,
    float* __restrict__ y, float* __restrict__ coll)
{
    const int t = threadIdx.x;
    const int w = t >> 6, lane = t & 63;
    const int tk = t >> 8;          // token this thread stages / combines
    const int t8 = t & 255;
    const size_t gt0 = (size_t)blockIdx.x * 2;

    __shared__ unsigned int xh[2][KD / 2];  // packed f16 x, 16 KB per token
    __shared__ float ssred[8];              // per-wave sumsq partials
    __shared__ float lg[2][24];             // raw dot products
    __shared__ float wts[2][24];            // 0..3 pre, 4..7 post, 8..23 comb

    // ---- phase 0: stage x into LDS as f16, sumsq from exact f32 ----
    {
        const float* xb = x + (gt0 + tk) * KD + t8 * 4;
        float ss = 0.f;
#pragma unroll
        for (int i = 0; i < 8; ++i) {
            float4 v = *reinterpret_cast<const float4*>(xb + i * 1024);
            ss += v.x * v.x + v.y * v.y + v.z * v.z + v.w * v.w;
            uint2 p; p.x = pk2(v.x, v.y); p.y = pk2(v.z, v.w);
            *reinterpret_cast<uint2*>(&xh[tk][i * 512 + t8 * 2]) = p;
        }
#pragma unroll
        for (int m = 1; m < 64; m <<= 1) ss += __shfl_xor(ss, m, 64);
        if (lane == 0) ssred[w] = ss;
    }
    __syncthreads();

    // ---- phase A: wave w -> rows 3w..3w+2, BOTH tokens (shared W load) ----
    {
        const int r0 = w * 3;
        float acc[3][2];
#pragma unroll
        for (int j = 0; j < 3; ++j) { acc[j][0] = 0.f; acc[j][1] = 0.f; }

        for (int it = 0; it < 16; ++it) {
            const int gi = it * 64 + lane;          // uint4 group = 8 f16
            uint4 xa = *reinterpret_cast<const uint4*>(&xh[0][gi * 4]);
            uint4 xb = *reinterpret_cast<const uint4*>(&xh[1][gi * 4]);
#pragma unroll
            for (int j = 0; j < 3; ++j) {
                if (FH) {
                    uint4 wv = *reinterpret_cast<const uint4*>(
                        Wh + ((size_t)(r0 + j) * 4096 + gi * 4));
                    acc[j][0] = dot2(wv.x, xa.x, acc[j][0]);
                    acc[j][0] = dot2(wv.y, xa.y, acc[j][0]);
                    acc[j][0] = dot2(wv.z, xa.z, acc[j][0]);
                    acc[j][0] = dot2(wv.w, xa.w, acc[j][0]);
                    acc[j][1] = dot2(wv.x, xb.x, acc[j][1]);
                    acc[j][1] = dot2(wv.y, xb.y, acc[j][1]);
                    acc[j][1] = dot2(wv.z, xb.z, acc[j][1]);
                    acc[j][1] = dot2(wv.w, xb.w, acc[j][1]);
                } else {
                    const float* wr = Wf + (size_t)(r0 + j) * KD + gi * 8;
                    float4 w0 = *reinterpret_cast<const float4*>(wr);
                    float4 w1 = *reinterpret_cast<const float4*>(wr + 4);
                    h2 a0 = __builtin_bit_cast(h2, xa.x), a1 = __builtin_bit_cast(h2, xa.y);
                    h2 a2 = __builtin_bit_cast(h2, xa.z), a3 = __builtin_bit_cast(h2, xa.w);
                    h2 b0 = __builtin_bit_cast(h2, xb.x), b1 = __builtin_bit_cast(h2, xb.y);
                    h2 b2 = __builtin_bit_cast(h2, xb.z), b3 = __builtin_bit_cast(h2, xb.w);
                    acc[j][0] += w0.x * (float)a0.x + w0.y * (float)a0.y
                               + w0.z * (float)a1.x + w0.w * (float)a1.y
                               + w1.x * (float)a2.x + w1.y * (float)a2.y
                               + w1.z * (float)a3.x + w1.w * (float)a3.y;
                    acc[j][1] += w0.x * (float)b0.x + w0.y * (float)b0.y
                               + w0.z * (float)b1.x + w0.w * (float)b1.y
                               + w1.x * (float)b2.x + w1.y * (float)b2.y
                               + w1.z * (float)b3.x + w1.w * (float)b3.y;
                }
            }
        }
#pragma unroll
        for (int j = 0; j < 3; ++j)
#pragma unroll
            for (int tt = 0; tt < 2; ++tt) {
                float v = acc[j][tt];
#pragma unroll
                for (int m = 1; m < 64; m <<= 1) v += __shfl_xor(v, m, 64);
                if (lane == 0) lg[tt][r0 + j] = v;
            }
    }
    __syncthreads();

    // ---- weights: 32 lanes (16 per token), sigmoid/softmax/sinkhorn ----
    if (t < 32) {
        const int wtk = t >> 4, idx = t & 15;     // idx = h*4 + k
        float ss = ssred[wtk * 4] + ssred[wtk * 4 + 1]
                 + ssred[wtk * 4 + 2] + ssred[wtk * 4 + 3];
        float rms = rsqrtf(ss * (1.f / 8192.f) + EPS);
        float s0 = scale[0], s1 = scale[1], s2 = scale[2];
        float cl = lg[wtk][8 + idx] * rms * s2 + base[8 + idx];
        float mx = fmaxf(cl, __shfl_xor(cl, 1, 64));
        mx = fmaxf(mx, __shfl_xor(mx, 2, 64));
        float e = expf(cl - mx);
        float se = e + __shfl_xor(e, 1, 64); se += __shfl_xor(se, 2, 64);
        float m = e / se + EPS;
        float cs = m + __shfl_xor(m, 4, 64); cs += __shfl_xor(cs, 8, 64);
        m = m / (cs + EPS);
#pragma unroll
        for (int it = 0; it < 19; ++it) {
            float rs = m + __shfl_xor(m, 1, 64); rs += __shfl_xor(rs, 2, 64);
            m = m / (rs + EPS);
            cs = m + __shfl_xor(m, 4, 64); cs += __shfl_xor(cs, 8, 64);
            m = m / (cs + EPS);
        }
        wts[wtk][8 + idx] = m;
        if (idx < 4) {
            float z = lg[wtk][idx] * rms * s0 + base[idx];
            wts[wtk][idx] = 1.f / (1.f + expf(-z)) + EPS;
        } else if (idx < 8) {
            float z = lg[wtk][idx] * rms * s1 + base[idx];
            wts[wtk][idx] = 2.f / (1.f + expf(-z));
        }
    }
    __syncthreads();

    // ---- phase B: outputs from f16 x in LDS ----
    float pre[4], post[4], cmb[4][4];
#pragma unroll
    for (int k = 0; k < 4; ++k) { pre[k] = wts[tk][k]; post[k] = wts[tk][4 + k]; }
#pragma unroll
    for (int h = 0; h < 4; ++h)
#pragma unroll
        for (int k = 0; k < 4; ++k) cmb[h][k] = wts[tk][8 + h * 4 + k];

    const float* ob = outp + (gt0 + tk) * D_;
    float* yb = y + (gt0 + tk) * KD;
    float* cb = coll + (gt0 + tk) * D_;

#pragma unroll
    for (int dh = 0; dh < 2; ++dh) {
        const int d = dh * 1024 + t8 * 4;
        float xk[4][4];
#pragma unroll
        for (int k = 0; k < 4; ++k) {
            uint2 p = *reinterpret_cast<const uint2*>(&xh[tk][k * 1024 + (d >> 1)]);
            h2 h0 = __builtin_bit_cast(h2, p.x), h1 = __builtin_bit_cast(h2, p.y);
            xk[k][0] = (float)h0.x; xk[k][1] = (float)h0.y;
            xk[k][2] = (float)h1.x; xk[k][3] = (float)h1.y;
        }
        float4 ov = *reinterpret_cast<const float4*>(ob + d);
        float cv[4], yv[4];
#pragma unroll
        for (int e = 0; e < 4; ++e)
            cv[e] = pre[0] * xk[0][e] + pre[1] * xk[1][e]
                  + pre[2] * xk[2][e] + pre[3] * xk[3][e];
        *reinterpret_cast<float4*>(cb + d) = make_float4(cv[0], cv[1], cv[2], cv[3]);
        const float oe[4] = {ov.x, ov.y, ov.z, ov.w};
#pragma unroll
        for (int h = 0; h < 4; ++h) {
#pragma unroll
            for (int e = 0; e < 4; ++e)
                yv[e] = post[h] * oe[e] + cmb[h][0] * xk[0][e] + cmb[h][1] * xk[1][e]
                      + cmb[h][2] * xk[2][e] + cmb[h][3] * xk[3][e];
            *reinterpret_cast<float4*>(yb + h * D_ + d) =
                make_float4(yv[0], yv[1], yv[2], yv[3]);
        }
    }
}

extern "C" void kernel_launch(void* const* d_in, const int* in_sizes, int n_in,
                              void* d_out, int out_size, void* d_ws, size_t ws_size,
                              hipStream_t stream) {
    const float* x     = (const float*)d_in[0];
    const float* outp  = (const float*)d_in[1];
    const float* W     = (const float*)d_in[2];
    const float* scale = (const float*)d_in[3];
    const float* base  = (const float*)d_in[4];
    float* y    = (float*)d_out;
    float* coll = y + (size_t)NTOK * KD;   // 67108864

    const size_t wh_bytes = (size_t)NOUT * KD * 2; // 384 KB f16
    if (ws_size >= wh_bytes) {
        unsigned int* Wh = (unsigned int*)d_ws;
        conv_w_kernel<<<NOUT * KD / 8 / 256, 256, 0, stream>>>(W, Wh);
        hypermix_kernel<true><<<NTOK / 2, TPB, 0, stream>>>(x, outp, Wh, W, scale, base, y, coll);
    } else {
        hypermix_kernel<false><<<NTOK / 2, TPB, 0, stream>>>(x, outp, nullptr, W, scale, base, y, coll);
    }
}

// Round 10
// 198.278 us; speedup vs baseline: 7.2544x; 2.3665x over previous
//
#include <hip/hip_runtime.h>

// HyperMixer fused kernel, MI355X (gfx950).
// x[B=2,S=4096,K=4,D=2048] f32, out[B,S,D] f32, W[24][8192] f32,
// scale[3], base[24]. Output = concat(y[B,S,K,D], collapsed[B,S,D]) f32.
//
// Round-10 = round-9 with BOUNDED UNROLL on the phase-A K-loop.
// Evidence trail: r7 cap32/r8 cap64/r9 cap128 -> WRITE 2.74/2.06/1.01 GB
// (real output is 0.33 GB): the constant-16-trip it-loop gets FULLY
// unrolled by the compiler, hoisting 16 iterations of LDS x-loads and W
// loads into one live set that spills at ANY reasonable VGPR budget.
// #pragma unroll 2 keeps ~2 iterations in flight (~60 live VGPRs).
// Algorithm (validated, absmax 0.03125): 2 tokens per 512-thread block;
// x staged in LDS as packed f16 (16 KB/token); W pre-converted f16
// (384 KB, L2-resident); wave w computes rows 3w..3w+2 for BOTH tokens
// (one W load serves 2 tokens); v_dot2_f32_f16 = 2 MACs/inst, no unpack.

#define EPS 1e-6f
constexpr int K_ = 4, D_ = 2048, KD = 8192, NOUT = 24;
constexpr int NTOK = 2 * 4096;          // 8192 tokens
constexpr int TPB = 512;

typedef _Float16 h2 __attribute__((ext_vector_type(2)));

static __device__ __forceinline__ unsigned int pk2(float a, float b) {
    h2 h; h.x = (_Float16)a; h.y = (_Float16)b;
    return __builtin_bit_cast(unsigned int, h);
}

static __device__ __forceinline__ float dot2(unsigned int w, unsigned int x, float c) {
#if __has_builtin(__builtin_amdgcn_fdot2)
    return __builtin_amdgcn_fdot2(__builtin_bit_cast(h2, w),
                                  __builtin_bit_cast(h2, x), c, false);
#else
    h2 hw = __builtin_bit_cast(h2, w), hx = __builtin_bit_cast(h2, x);
    return c + (float)hw.x * (float)hx.x + (float)hw.y * (float)hx.y;
#endif
}

// Wh: linear f16 of W. Thread g converts 8 consecutive floats.
__global__ void conv_w_kernel(const float* __restrict__ W, unsigned int* __restrict__ Wh) {
    int g = blockIdx.x * blockDim.x + threadIdx.x;   // 24576 threads
    const float* src = W + (size_t)g * 8;
    float4 a = *reinterpret_cast<const float4*>(src);
    float4 b = *reinterpret_cast<const float4*>(src + 4);
    uint4 u;
    u.x = pk2(a.x, a.y); u.y = pk2(a.z, a.w);
    u.z = pk2(b.x, b.y); u.w = pk2(b.z, b.w);
    *reinterpret_cast<uint4*>(Wh + (size_t)g * 4) = u;
}

template <bool FH>
__global__ __launch_bounds__(TPB) void hypermix_kernel(
    const float* __restrict__ x, const float* __restrict__ outp,
    const unsigned int* __restrict__ Wh, const float* __restrict__ Wf,
    const float* __restrict__ scale, const float* __restrict__ base,
    float* __restrict__ y, float* __restrict__ coll)
{
    const int t = threadIdx.x;
    const int w = t >> 6, lane = t & 63;
    const int tk = t >> 8;          // token this thread stages / combines
    const int t8 = t & 255;
    const size_t gt0 = (size_t)blockIdx.x * 2;

    __shared__ unsigned int xh[2][KD / 2];  // packed f16 x, 16 KB per token
    __shared__ float ssred[8];              // per-wave sumsq partials
    __shared__ float lg[2][24];             // raw dot products
    __shared__ float wts[2][24];            // 0..3 pre, 4..7 post, 8..23 comb

    // ---- phase 0: stage x into LDS as f16, sumsq from exact f32 ----
    {
        const float* xb = x + (gt0 + tk) * KD + t8 * 4;
        float ss = 0.f;
#pragma unroll 2
        for (int i = 0; i < 8; ++i) {
            float4 v = *reinterpret_cast<const float4*>(xb + i * 1024);
            ss += v.x * v.x + v.y * v.y + v.z * v.z + v.w * v.w;
            uint2 p; p.x = pk2(v.x, v.y); p.y = pk2(v.z, v.w);
            *reinterpret_cast<uint2*>(&xh[tk][i * 512 + t8 * 2]) = p;
        }
#pragma unroll
        for (int m = 1; m < 64; m <<= 1) ss += __shfl_xor(ss, m, 64);
        if (lane == 0) ssred[w] = ss;
    }
    __syncthreads();

    // ---- phase A: wave w -> rows 3w..3w+2, BOTH tokens (shared W load) ----
    {
        const int r0 = w * 3;
        float acc[3][2];
#pragma unroll
        for (int j = 0; j < 3; ++j) { acc[j][0] = 0.f; acc[j][1] = 0.f; }

#pragma unroll 2
        for (int it = 0; it < 16; ++it) {
            const int gi = it * 64 + lane;          // uint4 group = 8 f16
            uint4 xa = *reinterpret_cast<const uint4*>(&xh[0][gi * 4]);
            uint4 xb = *reinterpret_cast<const uint4*>(&xh[1][gi * 4]);
#pragma unroll
            for (int j = 0; j < 3; ++j) {
                if (FH) {
                    uint4 wv = *reinterpret_cast<const uint4*>(
                        Wh + ((size_t)(r0 + j) * 4096 + gi * 4));
                    acc[j][0] = dot2(wv.x, xa.x, acc[j][0]);
                    acc[j][0] = dot2(wv.y, xa.y, acc[j][0]);
                    acc[j][0] = dot2(wv.z, xa.z, acc[j][0]);
                    acc[j][0] = dot2(wv.w, xa.w, acc[j][0]);
                    acc[j][1] = dot2(wv.x, xb.x, acc[j][1]);
                    acc[j][1] = dot2(wv.y, xb.y, acc[j][1]);
                    acc[j][1] = dot2(wv.z, xb.z, acc[j][1]);
                    acc[j][1] = dot2(wv.w, xb.w, acc[j][1]);
                } else {
                    const float* wr = Wf + (size_t)(r0 + j) * KD + gi * 8;
                    float4 w0 = *reinterpret_cast<const float4*>(wr);
                    float4 w1 = *reinterpret_cast<const float4*>(wr + 4);
                    h2 a0 = __builtin_bit_cast(h2, xa.x), a1 = __builtin_bit_cast(h2, xa.y);
                    h2 a2 = __builtin_bit_cast(h2, xa.z), a3 = __builtin_bit_cast(h2, xa.w);
                    h2 b0 = __builtin_bit_cast(h2, xb.x), b1 = __builtin_bit_cast(h2, xb.y);
                    h2 b2 = __builtin_bit_cast(h2, xb.z), b3 = __builtin_bit_cast(h2, xb.w);
                    acc[j][0] += w0.x * (float)a0.x + w0.y * (float)a0.y
                               + w0.z * (float)a1.x + w0.w * (float)a1.y
                               + w1.x * (float)a2.x + w1.y * (float)a2.y
                               + w1.z * (float)a3.x + w1.w * (float)a3.y;
                    acc[j][1] += w0.x * (float)b0.x + w0.y * (float)b0.y
                               + w0.z * (float)b1.x + w0.w * (float)b1.y
                               + w1.x * (float)b2.x + w1.y * (float)b2.y
                               + w1.z * (float)b3.x + w1.w * (float)b3.y;
                }
            }
        }
#pragma unroll
        for (int j = 0; j < 3; ++j)
#pragma unroll
            for (int tt = 0; tt < 2; ++tt) {
                float v = acc[j][tt];
#pragma unroll
                for (int m = 1; m < 64; m <<= 1) v += __shfl_xor(v, m, 64);
                if (lane == 0) lg[tt][r0 + j] = v;
            }
    }
    __syncthreads();

    // ---- weights: 32 lanes (16 per token), sigmoid/softmax/sinkhorn ----
    if (t < 32) {
        const int wtk = t >> 4, idx = t & 15;     // idx = h*4 + k
        float ss = ssred[wtk * 4] + ssred[wtk * 4 + 1]
                 + ssred[wtk * 4 + 2] + ssred[wtk * 4 + 3];
        float rms = rsqrtf(ss * (1.f / 8192.f) + EPS);
        float s0 = scale[0], s1 = scale[1], s2 = scale[2];
        float cl = lg[wtk][8 + idx] * rms * s2 + base[8 + idx];
        float mx = fmaxf(cl, __shfl_xor(cl, 1, 64));
        mx = fmaxf(mx, __shfl_xor(mx, 2, 64));
        float e = expf(cl - mx);
        float se = e + __shfl_xor(e, 1, 64); se += __shfl_xor(se, 2, 64);
        float m = e / se + EPS;
        float cs = m + __shfl_xor(m, 4, 64); cs += __shfl_xor(cs, 8, 64);
        m = m / (cs + EPS);
#pragma unroll 1
        for (int it = 0; it < 19; ++it) {
            float rs = m + __shfl_xor(m, 1, 64); rs += __shfl_xor(rs, 2, 64);
            m = m / (rs + EPS);
            cs = m + __shfl_xor(m, 4, 64); cs += __shfl_xor(cs, 8, 64);
            m = m / (cs + EPS);
        }
        wts[wtk][8 + idx] = m;
        if (idx < 4) {
            float z = lg[wtk][idx] * rms * s0 + base[idx];
            wts[wtk][idx] = 1.f / (1.f + expf(-z)) + EPS;
        } else if (idx < 8) {
            float z = lg[wtk][idx] * rms * s1 + base[idx];
            wts[wtk][idx] = 2.f / (1.f + expf(-z));
        }
    }
    __syncthreads();

    // ---- phase B: outputs from f16 x in LDS ----
    float pre[4], post[4], cmb[4][4];
#pragma unroll
    for (int k = 0; k < 4; ++k) { pre[k] = wts[tk][k]; post[k] = wts[tk][4 + k]; }
#pragma unroll
    for (int h = 0; h < 4; ++h)
#pragma unroll
        for (int k = 0; k < 4; ++k) cmb[h][k] = wts[tk][8 + h * 4 + k];

    const float* ob = outp + (gt0 + tk) * D_;
    float* yb = y + (gt0 + tk) * KD;
    float* cb = coll + (gt0 + tk) * D_;

#pragma unroll 1
    for (int dh = 0; dh < 2; ++dh) {
        const int d = dh * 1024 + t8 * 4;
        float xk[4][4];
#pragma unroll
        for (int k = 0; k < 4; ++k) {
            uint2 p = *reinterpret_cast<const uint2*>(&xh[tk][k * 1024 + (d >> 1)]);
            h2 h0 = __builtin_bit_cast(h2, p.x), h1 = __builtin_bit_cast(h2, p.y);
            xk[k][0] = (float)h0.x; xk[k][1] = (float)h0.y;
            xk[k][2] = (float)h1.x; xk[k][3] = (float)h1.y;
        }
        float4 ov = *reinterpret_cast<const float4*>(ob + d);
        float cv[4], yv[4];
#pragma unroll
        for (int e = 0; e < 4; ++e)
            cv[e] = pre[0] * xk[0][e] + pre[1] * xk[1][e]
                  + pre[2] * xk[2][e] + pre[3] * xk[3][e];
        *reinterpret_cast<float4*>(cb + d) = make_float4(cv[0], cv[1], cv[2], cv[3]);
        const float oe[4] = {ov.x, ov.y, ov.z, ov.w};
#pragma unroll
        for (int h = 0; h < 4; ++h) {
#pragma unroll
            for (int e = 0; e < 4; ++e)
                yv[e] = post[h] * oe[e] + cmb[h][0] * xk[0][e] + cmb[h][1] * xk[1][e]
                      + cmb[h][2] * xk[2][e] + cmb[h][3] * xk[3][e];
            *reinterpret_cast<float4*>(yb + h * D_ + d) =
                make_float4(yv[0], yv[1], yv[2], yv[3]);
        }
    }
}

extern "C" void kernel_launch(void* const* d_in, const int* in_sizes, int n_in,
                              void* d_out, int out_size, void* d_ws, size_t ws_size,
                              hipStream_t stream) {
    const float* x     = (const float*)d_in[0];
    const float* outp  = (const float*)d_in[1];
    const float* W     = (const float*)d_in[2];
    const float* scale = (const float*)d_in[3];
    const float* base  = (const float*)d_in[4];
    float* y    = (float*)d_out;
    float* coll = y + (size_t)NTOK * KD;   // 67108864

    const size_t wh_bytes = (size_t)NOUT * KD * 2; // 384 KB f16
    if (ws_size >= wh_bytes) {
        unsigned int* Wh = (unsigned int*)d_ws;
        conv_w_kernel<<<NOUT * KD / 8 / 256, 256, 0, stream>>>(W, Wh);
        hypermix_kernel<true><<<NTOK / 2, TPB, 0, stream>>>(x, outp, Wh, W, scale, base, y, coll);
    } else {
        hypermix_kernel<false><<<NTOK / 2, TPB, 0, stream>>>(x, outp, nullptr, W, scale, base, y, coll);
    }
}

// Round 11
// 180.995 us; speedup vs baseline: 7.9472x; 1.0955x over previous
//
#include <hip/hip_runtime.h>

// HyperMixer fused kernel, MI355X (gfx950).
// x[B=2,S=4096,K=4,D=2048] f32, out[B,S,D] f32, W[24][8192] f32,
// scale[3], base[24]. Output = concat(y[B,S,K,D], collapsed[B,S,D]) f32.
//
// Round-11 = round-10 with 4 tokens per 512-thread block.
// r10 (2 tok/block): 198us, VALUBusy 24%, HBM 29% -> phase-A is
// L2-latency bound (24 dot2 wave-insts per 3 dependent W loads) and W L2
// traffic is 1.57 GB. 4 tokens doubles dot2-per-W-load (48:3) and halves
// W L2 traffic (2048 blocks x 384 KB = 0.79 GB). LDS 64KB+aux -> still
// 2 blocks/CU. Proven ingredients kept: f16 x in LDS, f16 W (L2-resident,
// one conv pre-pass), v_dot2_f32_f16, BOUNDED unroll (r9 lesson: full
// unroll of the 16-trip K-loop spills at any VGPR budget), bare
// __launch_bounds__ (r7/r8 lesson: arg2 caps VGPR as min-blocks/CU).

#define EPS 1e-6f
constexpr int K_ = 4, D_ = 2048, KD = 8192, NOUT = 24;
constexpr int NTOK = 2 * 4096;          // 8192 tokens
constexpr int TPB = 512;
constexpr int TOKS = 4;

typedef _Float16 h2 __attribute__((ext_vector_type(2)));

static __device__ __forceinline__ unsigned int pk2(float a, float b) {
    h2 h; h.x = (_Float16)a; h.y = (_Float16)b;
    return __builtin_bit_cast(unsigned int, h);
}

static __device__ __forceinline__ float dot2(unsigned int w, unsigned int x, float c) {
#if __has_builtin(__builtin_amdgcn_fdot2)
    return __builtin_amdgcn_fdot2(__builtin_bit_cast(h2, w),
                                  __builtin_bit_cast(h2, x), c, false);
#else
    h2 hw = __builtin_bit_cast(h2, w), hx = __builtin_bit_cast(h2, x);
    return c + (float)hw.x * (float)hx.x + (float)hw.y * (float)hx.y;
#endif
}

// Wh: linear f16 of W. Thread g converts 8 consecutive floats.
__global__ void conv_w_kernel(const float* __restrict__ W, unsigned int* __restrict__ Wh) {
    int g = blockIdx.x * blockDim.x + threadIdx.x;   // 24576 threads
    const float* src = W + (size_t)g * 8;
    float4 a = *reinterpret_cast<const float4*>(src);
    float4 b = *reinterpret_cast<const float4*>(src + 4);
    uint4 u;
    u.x = pk2(a.x, a.y); u.y = pk2(a.z, a.w);
    u.z = pk2(b.x, b.y); u.w = pk2(b.z, b.w);
    *reinterpret_cast<uint4*>(Wh + (size_t)g * 4) = u;
}

template <bool FH>
__global__ __launch_bounds__(TPB) void hypermix_kernel(
    const float* __restrict__ x, const float* __restrict__ outp,
    const unsigned int* __restrict__ Wh, const float* __restrict__ Wf,
    const float* __restrict__ scale, const float* __restrict__ base,
    float* __restrict__ y, float* __restrict__ coll)
{
    const int t = threadIdx.x;
    const int w = t >> 6, lane = t & 63;
    const int tk4 = t >> 7, t7 = t & 127;   // token lane-group for stage/combine
    const size_t gt0 = (size_t)blockIdx.x * TOKS;

    __shared__ unsigned int xh[TOKS][KD / 2];  // packed f16 x, 16 KB/token = 64 KB
    __shared__ float ssred[8];                 // per-wave sumsq partials
    __shared__ float lg[TOKS][24];             // raw dot products
    __shared__ float wts[TOKS][24];            // 0..3 pre, 4..7 post, 8..23 comb

    // ---- phase 0: stage x into LDS as f16, sumsq from exact f32 ----
    // wave w covers token w>>1 (128 threads/token), 64 f32 per thread
    {
        const float* xb = x + (gt0 + tk4) * KD + t7 * 4;
        float ss = 0.f;
#pragma unroll 2
        for (int i = 0; i < 16; ++i) {
            float4 v = *reinterpret_cast<const float4*>(xb + i * 512);
            ss += v.x * v.x + v.y * v.y + v.z * v.z + v.w * v.w;
            uint2 p; p.x = pk2(v.x, v.y); p.y = pk2(v.z, v.w);
            *reinterpret_cast<uint2*>(&xh[tk4][i * 256 + t7 * 2]) = p;
        }
#pragma unroll
        for (int m = 1; m < 64; m <<= 1) ss += __shfl_xor(ss, m, 64);
        if (lane == 0) ssred[w] = ss;
    }
    __syncthreads();

    // ---- phase A: wave w -> rows 3w..3w+2, ALL 4 tokens (shared W load) ----
    {
        const int r0 = w * 3;
        float acc[3][4];
#pragma unroll
        for (int j = 0; j < 3; ++j)
#pragma unroll
            for (int tt = 0; tt < 4; ++tt) acc[j][tt] = 0.f;

#pragma unroll 2
        for (int it = 0; it < 16; ++it) {
            const int gi = it * 64 + lane;          // uint4 group = 8 f16
            uint4 xv0 = *reinterpret_cast<const uint4*>(&xh[0][gi * 4]);
            uint4 xv1 = *reinterpret_cast<const uint4*>(&xh[1][gi * 4]);
            uint4 xv2 = *reinterpret_cast<const uint4*>(&xh[2][gi * 4]);
            uint4 xv3 = *reinterpret_cast<const uint4*>(&xh[3][gi * 4]);
#pragma unroll
            for (int j = 0; j < 3; ++j) {
                if (FH) {
                    uint4 wv = *reinterpret_cast<const uint4*>(
                        Wh + ((size_t)(r0 + j) * 4096 + gi * 4));
                    acc[j][0] = dot2(wv.x, xv0.x, acc[j][0]);
                    acc[j][0] = dot2(wv.y, xv0.y, acc[j][0]);
                    acc[j][0] = dot2(wv.z, xv0.z, acc[j][0]);
                    acc[j][0] = dot2(wv.w, xv0.w, acc[j][0]);
                    acc[j][1] = dot2(wv.x, xv1.x, acc[j][1]);
                    acc[j][1] = dot2(wv.y, xv1.y, acc[j][1]);
                    acc[j][1] = dot2(wv.z, xv1.z, acc[j][1]);
                    acc[j][1] = dot2(wv.w, xv1.w, acc[j][1]);
                    acc[j][2] = dot2(wv.x, xv2.x, acc[j][2]);
                    acc[j][2] = dot2(wv.y, xv2.y, acc[j][2]);
                    acc[j][2] = dot2(wv.z, xv2.z, acc[j][2]);
                    acc[j][2] = dot2(wv.w, xv2.w, acc[j][2]);
                    acc[j][3] = dot2(wv.x, xv3.x, acc[j][3]);
                    acc[j][3] = dot2(wv.y, xv3.y, acc[j][3]);
                    acc[j][3] = dot2(wv.z, xv3.z, acc[j][3]);
                    acc[j][3] = dot2(wv.w, xv3.w, acc[j][3]);
                } else {
                    const float* wr = Wf + (size_t)(r0 + j) * KD + gi * 8;
                    float4 w0 = *reinterpret_cast<const float4*>(wr);
                    float4 w1 = *reinterpret_cast<const float4*>(wr + 4);
                    unsigned int wa = pk2(w0.x, w0.y), wb = pk2(w0.z, w0.w);
                    unsigned int wc = pk2(w1.x, w1.y), wd = pk2(w1.z, w1.w);
                    acc[j][0] = dot2(wa, xv0.x, acc[j][0]);
                    acc[j][0] = dot2(wb, xv0.y, acc[j][0]);
                    acc[j][0] = dot2(wc, xv0.z, acc[j][0]);
                    acc[j][0] = dot2(wd, xv0.w, acc[j][0]);
                    acc[j][1] = dot2(wa, xv1.x, acc[j][1]);
                    acc[j][1] = dot2(wb, xv1.y, acc[j][1]);
                    acc[j][1] = dot2(wc, xv1.z, acc[j][1]);
                    acc[j][1] = dot2(wd, xv1.w, acc[j][1]);
                    acc[j][2] = dot2(wa, xv2.x, acc[j][2]);
                    acc[j][2] = dot2(wb, xv2.y, acc[j][2]);
                    acc[j][2] = dot2(wc, xv2.z, acc[j][2]);
                    acc[j][2] = dot2(wd, xv2.w, acc[j][2]);
                    acc[j][3] = dot2(wa, xv3.x, acc[j][3]);
                    acc[j][3] = dot2(wb, xv3.y, acc[j][3]);
                    acc[j][3] = dot2(wc, xv3.z, acc[j][3]);
                    acc[j][3] = dot2(wd, xv3.w, acc[j][3]);
                }
            }
        }
#pragma unroll
        for (int j = 0; j < 3; ++j)
#pragma unroll
            for (int tt = 0; tt < 4; ++tt) {
                float v = acc[j][tt];
#pragma unroll
                for (int m = 1; m < 64; m <<= 1) v += __shfl_xor(v, m, 64);
                if (lane == 0) lg[tt][r0 + j] = v;
            }
    }
    __syncthreads();

    // ---- weights: 64 lanes (16 per token), sigmoid/softmax/sinkhorn ----
    if (t < 64) {
        const int wtk = t >> 4, idx = t & 15;     // idx = h*4 + k
        float ss = ssred[2 * wtk] + ssred[2 * wtk + 1];
        float rms = rsqrtf(ss * (1.f / 8192.f) + EPS);
        float s0 = scale[0], s1 = scale[1], s2 = scale[2];
        float cl = lg[wtk][8 + idx] * rms * s2 + base[8 + idx];
        float mx = fmaxf(cl, __shfl_xor(cl, 1, 64));
        mx = fmaxf(mx, __shfl_xor(mx, 2, 64));
        float e = expf(cl - mx);
        float se = e + __shfl_xor(e, 1, 64); se += __shfl_xor(se, 2, 64);
        float m = e / se + EPS;
        float cs = m + __shfl_xor(m, 4, 64); cs += __shfl_xor(cs, 8, 64);
        m = m / (cs + EPS);
#pragma unroll 1
        for (int it = 0; it < 19; ++it) {
            float rs = m + __shfl_xor(m, 1, 64); rs += __shfl_xor(rs, 2, 64);
            m = m / (rs + EPS);
            cs = m + __shfl_xor(m, 4, 64); cs += __shfl_xor(cs, 8, 64);
            m = m / (cs + EPS);
        }
        wts[wtk][8 + idx] = m;
        if (idx < 4) {
            float z = lg[wtk][idx] * rms * s0 + base[idx];
            wts[wtk][idx] = 1.f / (1.f + expf(-z)) + EPS;
        } else if (idx < 8) {
            float z = lg[wtk][idx] * rms * s1 + base[idx];
            wts[wtk][idx] = 2.f / (1.f + expf(-z));
        }
    }
    __syncthreads();

    // ---- phase B: outputs from f16 x in LDS (128 threads per token) ----
    float pre[4], post[4], cmb[4][4];
#pragma unroll
    for (int k = 0; k < 4; ++k) { pre[k] = wts[tk4][k]; post[k] = wts[tk4][4 + k]; }
#pragma unroll
    for (int h = 0; h < 4; ++h)
#pragma unroll
        for (int k = 0; k < 4; ++k) cmb[h][k] = wts[tk4][8 + h * 4 + k];

    const float* ob = outp + (gt0 + tk4) * D_;
    float* yb = y + (gt0 + tk4) * KD;
    float* cb = coll + (gt0 + tk4) * D_;

#pragma unroll 1
    for (int dj = 0; dj < 4; ++dj) {
        const int d = dj * 512 + t7 * 4;
        float xk[4][4];
#pragma unroll
        for (int k = 0; k < 4; ++k) {
            uint2 p = *reinterpret_cast<const uint2*>(&xh[tk4][k * 1024 + (d >> 1)]);
            h2 h0 = __builtin_bit_cast(h2, p.x), h1 = __builtin_bit_cast(h2, p.y);
            xk[k][0] = (float)h0.x; xk[k][1] = (float)h0.y;
            xk[k][2] = (float)h1.x; xk[k][3] = (float)h1.y;
        }
        float4 ov = *reinterpret_cast<const float4*>(ob + d);
        float cv[4], yv[4];
#pragma unroll
        for (int e = 0; e < 4; ++e)
            cv[e] = pre[0] * xk[0][e] + pre[1] * xk[1][e]
                  + pre[2] * xk[2][e] + pre[3] * xk[3][e];
        *reinterpret_cast<float4*>(cb + d) = make_float4(cv[0], cv[1], cv[2], cv[3]);
        const float oe[4] = {ov.x, ov.y, ov.z, ov.w};
#pragma unroll
        for (int h = 0; h < 4; ++h) {
#pragma unroll
            for (int e = 0; e < 4; ++e)
                yv[e] = post[h] * oe[e] + cmb[h][0] * xk[0][e] + cmb[h][1] * xk[1][e]
                      + cmb[h][2] * xk[2][e] + cmb[h][3] * xk[3][e];
            *reinterpret_cast<float4*>(yb + h * D_ + d) =
                make_float4(yv[0], yv[1], yv[2], yv[3]);
        }
    }
}

extern "C" void kernel_launch(void* const* d_in, const int* in_sizes, int n_in,
                              void* d_out, int out_size, void* d_ws, size_t ws_size,
                              hipStream_t stream) {
    const float* x     = (const float*)d_in[0];
    const float* outp  = (const float*)d_in[1];
    const float* W     = (const float*)d_in[2];
    const float* scale = (const float*)d_in[3];
    const float* base  = (const float*)d_in[4];
    float* y    = (float*)d_out;
    float* coll = y + (size_t)NTOK * KD;   // 67108864

    const size_t wh_bytes = (size_t)NOUT * KD * 2; // 384 KB f16
    if (ws_size >= wh_bytes) {
        unsigned int* Wh = (unsigned int*)d_ws;
        conv_w_kernel<<<NOUT * KD / 8 / 256, 256, 0, stream>>>(W, Wh);
        hypermix_kernel<true><<<NTOK / TOKS, TPB, 0, stream>>>(x, outp, Wh, W, scale, base, y, coll);
    } else {
        hypermix_kernel<false><<<NTOK / TOKS, TPB, 0, stream>>>(x, outp, nullptr, W, scale, base, y, coll);
    }
}

// Round 12
// 177.389 us; speedup vs baseline: 8.1087x; 1.0203x over previous
//
#include <hip/hip_runtime.h>

// HyperMixer fused kernel, MI355X (gfx950).
// x[B=2,S=4096,K=4,D=2048] f32, out[B,S,D] f32, W[24][8192] f32,
// scale[3], base[24]. Output = concat(y[B,S,K,D], collapsed[B,S,D]) f32.
//
// Round-12 = round-11 with TOKS 4 -> 3 to lift occupancy.
// r11: 181us, occ 42% (LDS 65KB -> 2 blocks/CU), VALUBusy 22%, HBM 32%,
// fill-kernel proves 6.8 TB/s achievable -> stall-bound, need more waves.
// TOKS=3: LDS 49KB -> 3 blocks/CU = 24 waves/CU (+50% latency hiding) at
// the cost of W L2 traffic 0.79 -> 1.05 GB (~+8us, less than the hiding
// gain per r10->r11 measurement). Phases 0/B are clean all-thread token
// loops (512 thr x float4 = 2048 = D). Grid 2731, last block guards.
// Proven and kept: f16 x in LDS, f16 W (one conv pre-pass, L2-resident),
// v_dot2_f32_f16, bounded unroll 2 on the K-loop (full unroll spills),
// bare __launch_bounds__ (arg2 caps VGPR as min-blocks/CU).

#define EPS 1e-6f
constexpr int K_ = 4, D_ = 2048, KD = 8192, NOUT = 24;
constexpr int NTOK = 2 * 4096;          // 8192 tokens
constexpr int TPB = 512;
constexpr int TOKS = 3;
constexpr int NBLK = (NTOK + TOKS - 1) / TOKS;   // 2731

typedef _Float16 h2 __attribute__((ext_vector_type(2)));

static __device__ __forceinline__ unsigned int pk2(float a, float b) {
    h2 h; h.x = (_Float16)a; h.y = (_Float16)b;
    return __builtin_bit_cast(unsigned int, h);
}

static __device__ __forceinline__ float dot2(unsigned int w, unsigned int x, float c) {
#if __has_builtin(__builtin_amdgcn_fdot2)
    return __builtin_amdgcn_fdot2(__builtin_bit_cast(h2, w),
                                  __builtin_bit_cast(h2, x), c, false);
#else
    h2 hw = __builtin_bit_cast(h2, w), hx = __builtin_bit_cast(h2, x);
    return c + (float)hw.x * (float)hx.x + (float)hw.y * (float)hx.y;
#endif
}

// Wh: linear f16 of W. Thread g converts 8 consecutive floats.
__global__ void conv_w_kernel(const float* __restrict__ W, unsigned int* __restrict__ Wh) {
    int g = blockIdx.x * blockDim.x + threadIdx.x;   // 24576 threads
    const float* src = W + (size_t)g * 8;
    float4 a = *reinterpret_cast<const float4*>(src);
    float4 b = *reinterpret_cast<const float4*>(src + 4);
    uint4 u;
    u.x = pk2(a.x, a.y); u.y = pk2(a.z, a.w);
    u.z = pk2(b.x, b.y); u.w = pk2(b.z, b.w);
    *reinterpret_cast<uint4*>(Wh + (size_t)g * 4) = u;
}

template <bool FH>
__global__ __launch_bounds__(TPB) void hypermix_kernel(
    const float* __restrict__ x, const float* __restrict__ outp,
    const unsigned int* __restrict__ Wh, const float* __restrict__ Wf,
    const float* __restrict__ scale, const float* __restrict__ base,
    float* __restrict__ y, float* __restrict__ coll)
{
    const int t = threadIdx.x;
    const int w = t >> 6, lane = t & 63;
    const size_t gt0 = (size_t)blockIdx.x * TOKS;

    __shared__ unsigned int xh[TOKS][KD / 2];  // packed f16 x, 16 KB/token = 48 KB
    __shared__ float ssred[TOKS][8];           // per-wave sumsq partials
    __shared__ float lg[TOKS][24];             // raw dot products
    __shared__ float wts[TOKS][24];            // 0..3 pre, 4..7 post, 8..23 comb

    // ---- phase 0: stage each token with ALL 512 threads (4 float4 each) ----
#pragma unroll 1
    for (int tt = 0; tt < TOKS; ++tt) {
        float ss = 0.f;
        if (gt0 + tt < NTOK) {
            const float* xb = x + (gt0 + tt) * KD + t * 4;
#pragma unroll 2
            for (int i = 0; i < 4; ++i) {
                float4 v = *reinterpret_cast<const float4*>(xb + i * 2048);
                ss += v.x * v.x + v.y * v.y + v.z * v.z + v.w * v.w;
                uint2 p; p.x = pk2(v.x, v.y); p.y = pk2(v.z, v.w);
                *reinterpret_cast<uint2*>(&xh[tt][i * 1024 + t * 2]) = p;
            }
        }
#pragma unroll
        for (int m = 1; m < 64; m <<= 1) ss += __shfl_xor(ss, m, 64);
        if (lane == 0) ssred[tt][w] = ss;
    }
    __syncthreads();

    // ---- phase A: wave w -> rows 3w..3w+2, all TOKS tokens (shared W load) ----
    {
        const int r0 = w * 3;
        float acc[3][TOKS];
#pragma unroll
        for (int j = 0; j < 3; ++j)
#pragma unroll
            for (int tt = 0; tt < TOKS; ++tt) acc[j][tt] = 0.f;

#pragma unroll 2
        for (int it = 0; it < 16; ++it) {
            const int gi = it * 64 + lane;          // uint4 group = 8 f16
            uint4 xv0 = *reinterpret_cast<const uint4*>(&xh[0][gi * 4]);
            uint4 xv1 = *reinterpret_cast<const uint4*>(&xh[1][gi * 4]);
            uint4 xv2 = *reinterpret_cast<const uint4*>(&xh[2][gi * 4]);
#pragma unroll
            for (int j = 0; j < 3; ++j) {
                uint4 wv;
                if (FH) {
                    wv = *reinterpret_cast<const uint4*>(
                        Wh + ((size_t)(r0 + j) * 4096 + gi * 4));
                } else {
                    const float* wr = Wf + (size_t)(r0 + j) * KD + gi * 8;
                    float4 w0 = *reinterpret_cast<const float4*>(wr);
                    float4 w1 = *reinterpret_cast<const float4*>(wr + 4);
                    wv.x = pk2(w0.x, w0.y); wv.y = pk2(w0.z, w0.w);
                    wv.z = pk2(w1.x, w1.y); wv.w = pk2(w1.z, w1.w);
                }
                acc[j][0] = dot2(wv.x, xv0.x, acc[j][0]);
                acc[j][0] = dot2(wv.y, xv0.y, acc[j][0]);
                acc[j][0] = dot2(wv.z, xv0.z, acc[j][0]);
                acc[j][0] = dot2(wv.w, xv0.w, acc[j][0]);
                acc[j][1] = dot2(wv.x, xv1.x, acc[j][1]);
                acc[j][1] = dot2(wv.y, xv1.y, acc[j][1]);
                acc[j][1] = dot2(wv.z, xv1.z, acc[j][1]);
                acc[j][1] = dot2(wv.w, xv1.w, acc[j][1]);
                acc[j][2] = dot2(wv.x, xv2.x, acc[j][2]);
                acc[j][2] = dot2(wv.y, xv2.y, acc[j][2]);
                acc[j][2] = dot2(wv.z, xv2.z, acc[j][2]);
                acc[j][2] = dot2(wv.w, xv2.w, acc[j][2]);
            }
        }
#pragma unroll
        for (int j = 0; j < 3; ++j)
#pragma unroll
            for (int tt = 0; tt < TOKS; ++tt) {
                float v = acc[j][tt];
#pragma unroll
                for (int m = 1; m < 64; m <<= 1) v += __shfl_xor(v, m, 64);
                if (lane == 0) lg[tt][r0 + j] = v;
            }
    }
    __syncthreads();

    // ---- weights: 16 lanes per token, sigmoid/softmax/sinkhorn ----
    if (t < 16 * TOKS) {
        const int wtk = t >> 4, idx = t & 15;     // idx = h*4 + k
        float ss = 0.f;
#pragma unroll
        for (int i = 0; i < 8; ++i) ss += ssred[wtk][i];
        float rms = rsqrtf(ss * (1.f / 8192.f) + EPS);
        float s0 = scale[0], s1 = scale[1], s2 = scale[2];
        float cl = lg[wtk][8 + idx] * rms * s2 + base[8 + idx];
        float mx = fmaxf(cl, __shfl_xor(cl, 1, 64));
        mx = fmaxf(mx, __shfl_xor(mx, 2, 64));
        float e = expf(cl - mx);
        float se = e + __shfl_xor(e, 1, 64); se += __shfl_xor(se, 2, 64);
        float m = e / se + EPS;
        float cs = m + __shfl_xor(m, 4, 64); cs += __shfl_xor(cs, 8, 64);
        m = m / (cs + EPS);
#pragma unroll 1
        for (int it = 0; it < 19; ++it) {
            float rs = m + __shfl_xor(m, 1, 64); rs += __shfl_xor(rs, 2, 64);
            m = m / (rs + EPS);
            cs = m + __shfl_xor(m, 4, 64); cs += __shfl_xor(cs, 8, 64);
            m = m / (cs + EPS);
        }
        wts[wtk][8 + idx] = m;
        if (idx < 4) {
            float z = lg[wtk][idx] * rms * s0 + base[idx];
            wts[wtk][idx] = 1.f / (1.f + expf(-z)) + EPS;
        } else if (idx < 8) {
            float z = lg[wtk][idx] * rms * s1 + base[idx];
            wts[wtk][idx] = 2.f / (1.f + expf(-z));
        }
    }
    __syncthreads();

    // ---- phase B: per token, all 512 threads (one float4 column each) ----
#pragma unroll 1
    for (int tt = 0; tt < TOKS; ++tt) {
        if (gt0 + tt >= NTOK) continue;
        float pre[4], post[4], cmb[4][4];
#pragma unroll
        for (int k = 0; k < 4; ++k) { pre[k] = wts[tt][k]; post[k] = wts[tt][4 + k]; }
#pragma unroll
        for (int h = 0; h < 4; ++h)
#pragma unroll
            for (int k = 0; k < 4; ++k) cmb[h][k] = wts[tt][8 + h * 4 + k];

        const int d = t * 4;
        float xk[4][4];
#pragma unroll
        for (int k = 0; k < 4; ++k) {
            uint2 p = *reinterpret_cast<const uint2*>(&xh[tt][k * 1024 + t * 2]);
            h2 h0 = __builtin_bit_cast(h2, p.x), h1 = __builtin_bit_cast(h2, p.y);
            xk[k][0] = (float)h0.x; xk[k][1] = (float)h0.y;
            xk[k][2] = (float)h1.x; xk[k][3] = (float)h1.y;
        }
        const float* ob = outp + (gt0 + tt) * D_;
        float* yb = y + (gt0 + tt) * KD;
        float* cb = coll + (gt0 + tt) * D_;
        float4 ov = *reinterpret_cast<const float4*>(ob + d);
        float cv[4], yv[4];
#pragma unroll
        for (int e = 0; e < 4; ++e)
            cv[e] = pre[0] * xk[0][e] + pre[1] * xk[1][e]
                  + pre[2] * xk[2][e] + pre[3] * xk[3][e];
        *reinterpret_cast<float4*>(cb + d) = make_float4(cv[0], cv[1], cv[2], cv[3]);
        const float oe[4] = {ov.x, ov.y, ov.z, ov.w};
#pragma unroll
        for (int h = 0; h < 4; ++h) {
#pragma unroll
            for (int e = 0; e < 4; ++e)
                yv[e] = post[h] * oe[e] + cmb[h][0] * xk[0][e] + cmb[h][1] * xk[1][e]
                      + cmb[h][2] * xk[2][e] + cmb[h][3] * xk[3][e];
            *reinterpret_cast<float4*>(yb + h * D_ + d) =
                make_float4(yv[0], yv[1], yv[2], yv[3]);
        }
    }
}

extern "C" void kernel_launch(void* const* d_in, const int* in_sizes, int n_in,
                              void* d_out, int out_size, void* d_ws, size_t ws_size,
                              hipStream_t stream) {
    const float* x     = (const float*)d_in[0];
    const float* outp  = (const float*)d_in[1];
    const float* W     = (const float*)d_in[2];
    const float* scale = (const float*)d_in[3];
    const float* base  = (const float*)d_in[4];
    float* y    = (float*)d_out;
    float* coll = y + (size_t)NTOK * KD;   // 67108864

    const size_t wh_bytes = (size_t)NOUT * KD * 2; // 384 KB f16
    if (ws_size >= wh_bytes) {
        unsigned int* Wh = (unsigned int*)d_ws;
        conv_w_kernel<<<NOUT * KD / 8 / 256, 256, 0, stream>>>(W, Wh);
        hypermix_kernel<true><<<NBLK, TPB, 0, stream>>>(x, outp, Wh, W, scale, base, y, coll);
    } else {
        hypermix_kernel<false><<<NBLK, TPB, 0, stream>>>(x, outp, nullptr, W, scale, base, y, coll);
    }
}

// Round 13
// 175.509 us; speedup vs baseline: 8.1956x; 1.0107x over previous
//
#include <hip/hip_runtime.h>

// HyperMixer fused kernel, MI355X (gfx950).
// x[B=2,S=4096,K=4,D=2048] f32, out[B,S,D] f32, W[24][8192] f32,
// scale[3], base[24]. Output = concat(y[B,S,K,D], collapsed[B,S,D]) f32.
//
// Round-13 = round-12 (TOKS=3, f16 x in LDS, f16 W L2-resident, dot2)
// with the per-block serial critical path attacked:
//  - phase 0: ALL 12 x-loads + 3 out-prefetch loads issued before any
//    convert (r12 had unroll-2 -> 2 in flight x ~900cyc HBM latency)
//  - phase A: explicit 2-stage software pipeline with named register
//    stages (load it+1 while dotting it)
//  - weights: scalar per-token sinkhorn in 16 regs on 3 lanes with v_rcp
//    (r12: ~150 dependent shfl_xor x ~120cyc LDS-pipe = ~10K cyc serial
//    while the whole block waits at the barrier)
//  - butterfly reduces interleaved so their LDS chains overlap
// Evidence for this direction: r11->r12 occupancy 42->61.5% with ZERO
// duration change -> not TLP-starved; critical-path/serialization-bound.
// Kept lessons: bounded/manual unroll only (full unroll spills, r9),
// bare __launch_bounds__ (arg2 = min-blocks/CU VGPR cap, r7/r8).

#define EPS 1e-6f
constexpr int K_ = 4, D_ = 2048, KD = 8192, NOUT = 24;
constexpr int NTOK = 2 * 4096;          // 8192 tokens
constexpr int TPB = 512;
constexpr int TOKS = 3;
constexpr int NBLK = (NTOK + TOKS - 1) / TOKS;   // 2731

typedef _Float16 h2 __attribute__((ext_vector_type(2)));

static __device__ __forceinline__ unsigned int pk2(float a, float b) {
    h2 h; h.x = (_Float16)a; h.y = (_Float16)b;
    return __builtin_bit_cast(unsigned int, h);
}

static __device__ __forceinline__ float dot2(unsigned int w, unsigned int x, float c) {
#if __has_builtin(__builtin_amdgcn_fdot2)
    return __builtin_amdgcn_fdot2(__builtin_bit_cast(h2, w),
                                  __builtin_bit_cast(h2, x), c, false);
#else
    h2 hw = __builtin_bit_cast(h2, w), hx = __builtin_bit_cast(h2, x);
    return c + (float)hw.x * (float)hx.x + (float)hw.y * (float)hx.y;
#endif
}

static __device__ __forceinline__ float frcp(float v) {
#if __has_builtin(__builtin_amdgcn_rcpf)
    return __builtin_amdgcn_rcpf(v);
#else
    return 1.f / v;
#endif
}

// Wh: linear f16 of W. Thread g converts 8 consecutive floats.
__global__ void conv_w_kernel(const float* __restrict__ W, unsigned int* __restrict__ Wh) {
    int g = blockIdx.x * blockDim.x + threadIdx.x;   // 24576 threads
    const float* src = W + (size_t)g * 8;
    float4 a = *reinterpret_cast<const float4*>(src);
    float4 b = *reinterpret_cast<const float4*>(src + 4);
    uint4 u;
    u.x = pk2(a.x, a.y); u.y = pk2(a.z, a.w);
    u.z = pk2(b.x, b.y); u.w = pk2(b.z, b.w);
    *reinterpret_cast<uint4*>(Wh + (size_t)g * 4) = u;
}

__global__ __launch_bounds__(TPB) void hypermix_kernel(
    const float* __restrict__ x, const float* __restrict__ outp,
    const unsigned int* __restrict__ Wh,
    const float* __restrict__ scale, const float* __restrict__ base,
    float* __restrict__ y, float* __restrict__ coll)
{
    const int t = threadIdx.x;
    const int w = t >> 6, lane = t & 63;
    const size_t gt0 = (size_t)blockIdx.x * TOKS;
    const size_t tk0 = gt0;
    const size_t tk1 = (gt0 + 1 < NTOK) ? gt0 + 1 : NTOK - 1;
    const size_t tk2 = (gt0 + 2 < NTOK) ? gt0 + 2 : NTOK - 1;

    __shared__ unsigned int xh[TOKS][KD / 2];  // packed f16 x, 48 KB
    __shared__ float ssred[TOKS][8];           // per-wave sumsq partials
    __shared__ float lg[TOKS][24];             // raw dot products
    __shared__ float wts[TOKS][24];            // 0..3 pre, 4..7 post, 8..23 comb

    // ---- phase 0: issue ALL loads first (12 x float4 + 3 out float4) ----
    float4 v0[4], v1[4], v2[4], ov0, ov1, ov2;
    {
        const float* xb0 = x + tk0 * KD + t * 4;
        const float* xb1 = x + tk1 * KD + t * 4;
        const float* xb2 = x + tk2 * KD + t * 4;
#pragma unroll
        for (int i = 0; i < 4; ++i) v0[i] = *reinterpret_cast<const float4*>(xb0 + i * 2048);
#pragma unroll
        for (int i = 0; i < 4; ++i) v1[i] = *reinterpret_cast<const float4*>(xb1 + i * 2048);
#pragma unroll
        for (int i = 0; i < 4; ++i) v2[i] = *reinterpret_cast<const float4*>(xb2 + i * 2048);
        ov0 = *reinterpret_cast<const float4*>(outp + tk0 * D_ + t * 4);
        ov1 = *reinterpret_cast<const float4*>(outp + tk1 * D_ + t * 4);
        ov2 = *reinterpret_cast<const float4*>(outp + tk2 * D_ + t * 4);

        float ss0 = 0.f, ss1 = 0.f, ss2 = 0.f;
#pragma unroll
        for (int i = 0; i < 4; ++i) {
            ss0 += v0[i].x * v0[i].x + v0[i].y * v0[i].y + v0[i].z * v0[i].z + v0[i].w * v0[i].w;
            ss1 += v1[i].x * v1[i].x + v1[i].y * v1[i].y + v1[i].z * v1[i].z + v1[i].w * v1[i].w;
            ss2 += v2[i].x * v2[i].x + v2[i].y * v2[i].y + v2[i].z * v2[i].z + v2[i].w * v2[i].w;
            uint2 p0; p0.x = pk2(v0[i].x, v0[i].y); p0.y = pk2(v0[i].z, v0[i].w);
            uint2 p1; p1.x = pk2(v1[i].x, v1[i].y); p1.y = pk2(v1[i].z, v1[i].w);
            uint2 p2; p2.x = pk2(v2[i].x, v2[i].y); p2.y = pk2(v2[i].z, v2[i].w);
            *reinterpret_cast<uint2*>(&xh[0][i * 1024 + t * 2]) = p0;
            *reinterpret_cast<uint2*>(&xh[1][i * 1024 + t * 2]) = p1;
            *reinterpret_cast<uint2*>(&xh[2][i * 1024 + t * 2]) = p2;
        }
        // interleaved butterfly chains (overlapped LDS-pipe latency)
#pragma unroll
        for (int m = 1; m < 64; m <<= 1) {
            ss0 += __shfl_xor(ss0, m, 64);
            ss1 += __shfl_xor(ss1, m, 64);
            ss2 += __shfl_xor(ss2, m, 64);
        }
        if (lane == 0) { ssred[0][w] = ss0; ssred[1][w] = ss1; ssred[2][w] = ss2; }
    }
    __syncthreads();

    // ---- phase A: wave w -> rows 3w..3w+2, 2-stage software pipeline ----
    {
        const int r0 = w * 3;
        const unsigned int* Wp0 = Wh + (size_t)(r0 + 0) * 4096;
        const unsigned int* Wp1 = Wh + (size_t)(r0 + 1) * 4096;
        const unsigned int* Wp2 = Wh + (size_t)(r0 + 2) * 4096;
        float a00 = 0.f, a01 = 0.f, a02 = 0.f;
        float a10 = 0.f, a11 = 0.f, a12 = 0.f;
        float a20 = 0.f, a21 = 0.f, a22 = 0.f;
        uint4 xa0, xa1, xa2, wa0, wa1, wa2;
        uint4 xb0, xb1, xb2, wb0, wb1, wb2;

#define LOADIT(X0, X1, X2, W0, W1, W2, IT) do {                              \
        const int gi4 = ((IT) * 64 + lane) * 4;                              \
        X0 = *reinterpret_cast<const uint4*>(&xh[0][gi4]);                   \
        X1 = *reinterpret_cast<const uint4*>(&xh[1][gi4]);                   \
        X2 = *reinterpret_cast<const uint4*>(&xh[2][gi4]);                   \
        W0 = *reinterpret_cast<const uint4*>(Wp0 + gi4);                     \
        W1 = *reinterpret_cast<const uint4*>(Wp1 + gi4);                     \
        W2 = *reinterpret_cast<const uint4*>(Wp2 + gi4);                     \
    } while (0)
#define DOT4(A, WV, XV) do {                                                 \
        A = dot2(WV.x, XV.x, A); A = dot2(WV.y, XV.y, A);                    \
        A = dot2(WV.z, XV.z, A); A = dot2(WV.w, XV.w, A);                    \
    } while (0)
#define CONSUME(X0, X1, X2, W0, W1, W2) do {                                 \
        DOT4(a00, W0, X0); DOT4(a01, W0, X1); DOT4(a02, W0, X2);             \
        DOT4(a10, W1, X0); DOT4(a11, W1, X1); DOT4(a12, W1, X2);             \
        DOT4(a20, W2, X0); DOT4(a21, W2, X1); DOT4(a22, W2, X2);             \
    } while (0)

        LOADIT(xa0, xa1, xa2, wa0, wa1, wa2, 0);
#pragma unroll 1
        for (int it2 = 0; it2 < 7; ++it2) {
            LOADIT(xb0, xb1, xb2, wb0, wb1, wb2, 2 * it2 + 1);
            CONSUME(xa0, xa1, xa2, wa0, wa1, wa2);
            LOADIT(xa0, xa1, xa2, wa0, wa1, wa2, 2 * it2 + 2);
            CONSUME(xb0, xb1, xb2, wb0, wb1, wb2);
        }
        LOADIT(xb0, xb1, xb2, wb0, wb1, wb2, 15);
        CONSUME(xa0, xa1, xa2, wa0, wa1, wa2);
        CONSUME(xb0, xb1, xb2, wb0, wb1, wb2);
#undef LOADIT
#undef DOT4
#undef CONSUME

        // 9 interleaved butterfly chains
#pragma unroll
        for (int m = 1; m < 64; m <<= 1) {
            a00 += __shfl_xor(a00, m, 64); a01 += __shfl_xor(a01, m, 64);
            a02 += __shfl_xor(a02, m, 64); a10 += __shfl_xor(a10, m, 64);
            a11 += __shfl_xor(a11, m, 64); a12 += __shfl_xor(a12, m, 64);
            a20 += __shfl_xor(a20, m, 64); a21 += __shfl_xor(a21, m, 64);
            a22 += __shfl_xor(a22, m, 64);
        }
        if (lane == 0) {
            lg[0][r0] = a00;     lg[1][r0] = a01;     lg[2][r0] = a02;
            lg[0][r0 + 1] = a10; lg[1][r0 + 1] = a11; lg[2][r0 + 1] = a12;
            lg[0][r0 + 2] = a20; lg[1][r0 + 2] = a21; lg[2][r0 + 2] = a22;
        }
    }
    __syncthreads();

    // ---- weights: scalar per-token (3 lanes), sinkhorn fully in regs ----
    if (t < TOKS && gt0 + t < NTOK) {
        float ss = ssred[t][0] + ssred[t][1] + ssred[t][2] + ssred[t][3]
                 + ssred[t][4] + ssred[t][5] + ssred[t][6] + ssred[t][7];
        float rms = rsqrtf(ss * (1.f / 8192.f) + EPS);
        float s0 = scale[0], s1 = scale[1], s2 = scale[2];
        float l[24];
#pragma unroll
        for (int i = 0; i < 24; ++i) l[i] = lg[t][i];
#pragma unroll
        for (int k = 0; k < 4; ++k) {
            float z0 = l[k] * rms * s0 + base[k];
            wts[t][k] = frcp(1.f + __expf(-z0)) + EPS;
            float z1 = l[4 + k] * rms * s1 + base[4 + k];
            wts[t][4 + k] = 2.f * frcp(1.f + __expf(-z1));
        }
        float p[16];
#pragma unroll
        for (int h = 0; h < 4; ++h) {
            float c0 = l[8 + h * 4 + 0] * rms * s2 + base[8 + h * 4 + 0];
            float c1 = l[8 + h * 4 + 1] * rms * s2 + base[8 + h * 4 + 1];
            float c2 = l[8 + h * 4 + 2] * rms * s2 + base[8 + h * 4 + 2];
            float c3 = l[8 + h * 4 + 3] * rms * s2 + base[8 + h * 4 + 3];
            float mx = fmaxf(fmaxf(c0, c1), fmaxf(c2, c3));
            float e0 = __expf(c0 - mx), e1 = __expf(c1 - mx);
            float e2 = __expf(c2 - mx), e3 = __expf(c3 - mx);
            float inv = frcp(e0 + e1 + e2 + e3);
            p[h * 4 + 0] = e0 * inv + EPS; p[h * 4 + 1] = e1 * inv + EPS;
            p[h * 4 + 2] = e2 * inv + EPS; p[h * 4 + 3] = e3 * inv + EPS;
        }
        // priming column normalize
#pragma unroll
        for (int k = 0; k < 4; ++k) {
            float inv = frcp(p[k] + p[4 + k] + p[8 + k] + p[12 + k] + EPS);
            p[k] *= inv; p[4 + k] *= inv; p[8 + k] *= inv; p[12 + k] *= inv;
        }
#pragma unroll 1
        for (int itn = 0; itn < 19; ++itn) {
#pragma unroll
            for (int h = 0; h < 4; ++h) {
                float inv = frcp(p[h * 4] + p[h * 4 + 1] + p[h * 4 + 2] + p[h * 4 + 3] + EPS);
                p[h * 4] *= inv; p[h * 4 + 1] *= inv; p[h * 4 + 2] *= inv; p[h * 4 + 3] *= inv;
            }
#pragma unroll
            for (int k = 0; k < 4; ++k) {
                float inv = frcp(p[k] + p[4 + k] + p[8 + k] + p[12 + k] + EPS);
                p[k] *= inv; p[4 + k] *= inv; p[8 + k] *= inv; p[12 + k] *= inv;
            }
        }
#pragma unroll
        for (int i = 0; i < 16; ++i) wts[t][8 + i] = p[i];
    }
    __syncthreads();

    // ---- phase B: per token, all 512 threads, out already in regs ----
#define PHASEB(TT, OV) do {                                                  \
    if (gt0 + TT < NTOK) {                                                   \
        float pre[4], post[4], cmb[4][4];                                    \
        _Pragma("unroll")                                                    \
        for (int k = 0; k < 4; ++k) { pre[k] = wts[TT][k]; post[k] = wts[TT][4 + k]; } \
        _Pragma("unroll")                                                    \
        for (int h = 0; h < 4; ++h)                                          \
            _Pragma("unroll")                                                \
            for (int k = 0; k < 4; ++k) cmb[h][k] = wts[TT][8 + h * 4 + k];  \
        const int d = t * 4;                                                 \
        float xk[4][4];                                                      \
        _Pragma("unroll")                                                    \
        for (int k = 0; k < 4; ++k) {                                        \
            uint2 pq = *reinterpret_cast<const uint2*>(&xh[TT][k * 1024 + t * 2]); \
            h2 h0 = __builtin_bit_cast(h2, pq.x), h1 = __builtin_bit_cast(h2, pq.y); \
            xk[k][0] = (float)h0.x; xk[k][1] = (float)h0.y;                  \
            xk[k][2] = (float)h1.x; xk[k][3] = (float)h1.y;                  \
        }                                                                    \
        float* yb = y + (gt0 + TT) * KD;                                     \
        float* cb = coll + (gt0 + TT) * D_;                                  \
        float cv[4], yv[4];                                                  \
        _Pragma("unroll")                                                    \
        for (int e = 0; e < 4; ++e)                                          \
            cv[e] = pre[0] * xk[0][e] + pre[1] * xk[1][e]                    \
                  + pre[2] * xk[2][e] + pre[3] * xk[3][e];                   \
        *reinterpret_cast<float4*>(cb + d) = make_float4(cv[0], cv[1], cv[2], cv[3]); \
        const float oe[4] = {OV.x, OV.y, OV.z, OV.w};                        \
        _Pragma("unroll")                                                    \
        for (int h = 0; h < 4; ++h) {                                        \
            _Pragma("unroll")                                                \
            for (int e = 0; e < 4; ++e)                                      \
                yv[e] = post[h] * oe[e] + cmb[h][0] * xk[0][e] + cmb[h][1] * xk[1][e] \
                      + cmb[h][2] * xk[2][e] + cmb[h][3] * xk[3][e];         \
            *reinterpret_cast<float4*>(yb + h * D_ + d) =                    \
                make_float4(yv[0], yv[1], yv[2], yv[3]);                     \
        }                                                                    \
    } } while (0)

    PHASEB(0, ov0);
    PHASEB(1, ov1);
    PHASEB(2, ov2);
#undef PHASEB
}

extern "C" void kernel_launch(void* const* d_in, const int* in_sizes, int n_in,
                              void* d_out, int out_size, void* d_ws, size_t ws_size,
                              hipStream_t stream) {
    const float* x     = (const float*)d_in[0];
    const float* outp  = (const float*)d_in[1];
    const float* W     = (const float*)d_in[2];
    const float* scale = (const float*)d_in[3];
    const float* base  = (const float*)d_in[4];
    float* y    = (float*)d_out;
    float* coll = y + (size_t)NTOK * KD;   // 67108864

    unsigned int* Wh = (unsigned int*)d_ws;     // 384 KB f16 (ws is larger)
    conv_w_kernel<<<NOUT * KD / 8 / 256, 256, 0, stream>>>(W, Wh);
    hypermix_kernel<<<NBLK, TPB, 0, stream>>>(x, outp, Wh, scale, base, y, coll);
}